// Round 1
// 195.631 us; speedup vs baseline: 1.0312x; 1.0312x over previous
//
#include <hip/hip_runtime.h>
#include <hip/hip_bf16.h>

typedef __attribute__((ext_vector_type(8))) short bf16x8;
typedef __attribute__((ext_vector_type(4))) float f32x4;

#define B_DIM  2
#define S_DIM  2048
#define D_DIM  1024
#define H_DIM  16
#define HD_DIM 64

__device__ __forceinline__ float bf2f(ushort u) {
    union { unsigned int ui; float f; } c; c.ui = ((unsigned int)u) << 16; return c.f;
}
__device__ __forceinline__ ushort f2bf(float f) {
    __hip_bfloat16 h = __float2bfloat16(f);
    return *reinterpret_cast<ushort*>(&h);
}

// Async global->LDS DMA, 16 B per lane. LDS dest = wave-uniform base + lane*16.
__device__ __forceinline__ void async_cp16(const ushort* g, ushort* l) {
    __builtin_amdgcn_global_load_lds(
        (const __attribute__((address_space(1))) void*)g,
        (__attribute__((address_space(3))) void*)l, 16, 0, 0);
}

// ---------------------------------------------------------------------------
// Dtype detector: valid bf16 inputs never have exponent bits 0xFF; fp32 read
// as u16 halves hits 0xFF with p~1/256. flag=1 -> fp32 inputs, 0 -> bf16.
// ---------------------------------------------------------------------------
__global__ __launch_bounds__(256) void detect_kernel(const ushort* __restrict__ x,
                                                     int* __restrict__ flag) {
    __shared__ int any;
    int tid = threadIdx.x;
    if (tid == 0) any = 0;
    __syncthreads();
    int cnt = 0;
    for (int j = 0; j < 64; ++j) {
        ushort u = x[tid * 64 + j];
        if (((u >> 7) & 0xFF) == 0xFF) cnt++;
    }
    if (cnt) atomicOr(&any, 1);
    __syncthreads();
    if (tid == 0) *flag = any ? 1 : 0;
}

// ---------------------------------------------------------------------------
// Merged prep: grid (16,16,6).
//   z in 0..3 : convert + transpose weight z (Q/K/V -> Wqkvt slices, O -> Wot)
//   z == 4   : canonicalize x -> bf16 (4M elems)
//   z == 5   : biases -> fp32 (first 16 blocks)
// ---------------------------------------------------------------------------
__global__ __launch_bounds__(256) void prep_kernel(const void* __restrict__ x,
                                                   const void* __restrict__ Wq,
                                                   const void* __restrict__ Wk,
                                                   const void* __restrict__ Wv,
                                                   const void* __restrict__ Wo,
                                                   const void* __restrict__ bq,
                                                   const void* __restrict__ bk,
                                                   const void* __restrict__ bv,
                                                   const void* __restrict__ bo,
                                                   ushort* __restrict__ xc,
                                                   ushort* __restrict__ Wqkvt,
                                                   ushort* __restrict__ Wot,
                                                   float* __restrict__ biasf,
                                                   const int* __restrict__ flag) {
    int tid = threadIdx.x;
    int z = blockIdx.z;
    bool isf32 = (*flag != 0);

    if (z == 4) {
        int t = (blockIdx.y * 16 + blockIdx.x) * 256 + tid;   // 0..65535
#pragma unroll
        for (int c = 0; c < 8; ++c) {
            int i = t + c * 65536;                            // elem8 index
            if (isf32) {
                const float* s = (const float*)x;
                f32x4 a = *(const f32x4*)&s[(size_t)i * 8];
                f32x4 b = *(const f32x4*)&s[(size_t)i * 8 + 4];
                bf16x8 o;
                o[0] = f2bf(a.x); o[1] = f2bf(a.y); o[2] = f2bf(a.z); o[3] = f2bf(a.w);
                o[4] = f2bf(b.x); o[5] = f2bf(b.y); o[6] = f2bf(b.z); o[7] = f2bf(b.w);
                *(bf16x8*)&xc[(size_t)i * 8] = o;
            } else {
                *(bf16x8*)&xc[(size_t)i * 8] =
                    *(const bf16x8*)&((const ushort*)x)[(size_t)i * 8];
            }
        }
        return;
    }
    if (z == 5) {
        int bid = blockIdx.y * 16 + blockIdx.x;
        if (bid >= 16) return;
        int i = bid * 256 + tid;                              // 0..4095
        int w = i >> 10, j = i & 1023;
        const void* s = (w == 0) ? bq : (w == 1) ? bk : (w == 2) ? bv : bo;
        biasf[i] = isf32 ? ((const float*)s)[j] : bf2f(((const ushort*)s)[j]);
        return;
    }

    // weight transpose
    __shared__ ushort tile[64][72];
    const void* src = (z == 0) ? Wq : (z == 1) ? Wk : (z == 2) ? Wv : Wo;
    ushort* dst = (z < 3) ? (Wqkvt + (size_t)z * D_DIM * D_DIM) : Wot;
    int r0 = blockIdx.y * 64, c0 = blockIdx.x * 64;
#pragma unroll
    for (int p = 0; p < 2; ++p) {
        int r = p * 32 + (tid >> 3);
        int c = (tid & 7) * 8;
        if (isf32) {
            const float* s = (const float*)src;
            f32x4 a = *(const f32x4*)&s[(size_t)(r0 + r) * D_DIM + c0 + c];
            f32x4 b = *(const f32x4*)&s[(size_t)(r0 + r) * D_DIM + c0 + c + 4];
            tile[r][c + 0] = f2bf(a.x); tile[r][c + 1] = f2bf(a.y);
            tile[r][c + 2] = f2bf(a.z); tile[r][c + 3] = f2bf(a.w);
            tile[r][c + 4] = f2bf(b.x); tile[r][c + 5] = f2bf(b.y);
            tile[r][c + 6] = f2bf(b.z); tile[r][c + 7] = f2bf(b.w);
        } else {
            *(bf16x8*)&tile[r][c] =
                *(const bf16x8*)&((const ushort*)src)[(size_t)(r0 + r) * D_DIM + c0 + c];
        }
    }
    __syncthreads();
#pragma unroll
    for (int p = 0; p < 2; ++p) {
        int n  = p * 32 + (tid >> 3);
        int cc = (tid & 7) * 8;
        bf16x8 v;
#pragma unroll
        for (int e = 0; e < 8; ++e) v[e] = (short)tile[cc + e][n];
        *(bf16x8*)&dst[(size_t)(c0 + n) * D_DIM + r0 + cc] = v;
    }
}

// ---------------------------------------------------------------------------
// Fused QKV GEMM: 128x128 tile, BK=64, global_load_lds(16B), XOR swizzle
// (0 bank conflicts). Ncols=3072. Q slice pre-scaled by 0.125*log2(e);
// Q/K slices -> (BH,S,64) bf16; V slice -> TRANSPOSED (BH,64,S) bf16 directly
// (packed 8B stores; 16 rows x 32B per wave-store: L2-merged).
// ---------------------------------------------------------------------------
__global__ __launch_bounds__(256) void gemm128_kernel(const ushort* __restrict__ A,
                                                      const ushort* __restrict__ Bt,
                                                      const float* __restrict__ bias,
                                                      ushort* __restrict__ qkout,
                                                      ushort* __restrict__ vtout) {
    __shared__ ushort As[128 * 64];   // 16 KiB, unpadded
    __shared__ ushort Bs[128 * 64];
    int tid  = threadIdx.x;
    int wave = tid >> 6;
    int lane = tid & 63;
    int l16  = lane & 15;
    int quad = lane >> 4;
    int m0   = blockIdx.y * 128;
    int n0   = blockIdx.x * 128;
    int wm   = wave >> 1;
    int wn   = wave & 1;
    const int K = 1024;

    f32x4 acc[4][4];
#pragma unroll
    for (int i = 0; i < 4; ++i)
#pragma unroll
        for (int j = 0; j < 4; ++j) acc[i][j] = (f32x4){0.f, 0.f, 0.f, 0.f};

    int lrow = lane >> 3;                         // 0..7 row within chunk
    int gcol = ((lane & 7) ^ lrow) * 8;           // swizzled column (elems)
    int sw   = l16 & 7;                           // fragment-read swizzle

    for (int kt = 0; kt < 16; ++kt) {
        int k0 = kt * 64;
#pragma unroll
        for (int j = 0; j < 4; ++j) {
            int chunk = wave * 4 + j;             // 0..15; 8 rows each
            int grow  = chunk * 8 + lrow;
            async_cp16(&A[(size_t)(m0 + grow) * K + k0 + gcol], &As[chunk * 512]);
            async_cp16(&Bt[(size_t)(n0 + grow) * K + k0 + gcol], &Bs[chunk * 512]);
        }
        __syncthreads();

#pragma unroll
        for (int kb = 0; kb < 2; ++kb) {
            bf16x8 af[4], bf[4];
#pragma unroll
            for (int i = 0; i < 4; ++i)
                af[i] = *(const bf16x8*)&As[(wm * 64 + i * 16 + l16) * 64 +
                                            (((kb * 4 + quad) ^ sw) << 3)];
#pragma unroll
            for (int j = 0; j < 4; ++j)
                bf[j] = *(const bf16x8*)&Bs[(wn * 64 + j * 16 + l16) * 64 +
                                            (((kb * 4 + quad) ^ sw) << 3)];
#pragma unroll
            for (int i = 0; i < 4; ++i)
#pragma unroll
                for (int j = 0; j < 4; ++j)
                    acc[i][j] = __builtin_amdgcn_mfma_f32_16x16x32_bf16(af[i], bf[j],
                                                                        acc[i][j], 0, 0, 0);
        }
        __syncthreads();
    }

    const size_t TSZ = (size_t)B_DIM * H_DIM * S_DIM * HD_DIM;   // 4 Mi elems
#pragma unroll
    for (int j = 0; j < 4; ++j) {
        int n = n0 + wn * 64 + j * 16 + l16;        // C/D col = lane&15
        float bv = bias[n];
        int which = n >> 10;                        // 0=Q 1=K 2=V
        int n1 = n & 1023;
        int h = n1 >> 6, hd = n1 & 63;
#pragma unroll
        for (int i = 0; i < 4; ++i) {
            int mb = m0 + wm * 64 + i * 16 + quad * 4;     // row base (quad*4)
            int b = mb >> 11, s = mb & (S_DIM - 1);
            float v4[4];
#pragma unroll
            for (int r = 0; r < 4; ++r) v4[r] = acc[i][j][r] + bv;
            if (which == 2) {
                // V -> transposed (BH,64,S): 4 consecutive s, packed 8B store
                ushort pk[4];
#pragma unroll
                for (int r = 0; r < 4; ++r) pk[r] = f2bf(v4[r]);
                *(uint2*)&vtout[(((size_t)(b * H_DIM + h) * HD_DIM + hd)) * S_DIM + s] =
                    *(uint2*)pk;
            } else {
#pragma unroll
                for (int r = 0; r < 4; ++r) {
                    float v = v4[r];
                    // fold softmax scale AND log2(e) into Q (attn uses exp2)
                    if (which == 0) v *= 0.18033688011f;   // 0.125 * log2(e)
                    qkout[which * TSZ +
                          ((((size_t)(b * H_DIM + h)) * S_DIM + s + r) << 6) + hd] = f2bf(v);
                }
            }
        }
    }
}

// ---------------------------------------------------------------------------
// O-projection GEMM: 64x128 tile (M x N), BK=64, same staging/swizzle.
// Grid (8, 64) = 512 blocks -> 2 blocks/CU (vs 1 for the 128x128 shape):
// co-resident block overlaps the barrier's vmcnt drain. 4 waves side-by-side
// in N; per wave acc = 4(m) x 2(n) frags.
// out: bf16 or fp32 per *flag, row-major M x 1024.
// ---------------------------------------------------------------------------
__global__ __launch_bounds__(256) void gemm64_kernel(const ushort* __restrict__ A,
                                                     const ushort* __restrict__ Bt,
                                                     const float* __restrict__ bias,
                                                     void* __restrict__ out,
                                                     const int* __restrict__ flag) {
    __shared__ ushort As[64 * 64];    // 8 KiB
    __shared__ ushort Bs[128 * 64];   // 16 KiB
    int tid  = threadIdx.x;
    int wave = tid >> 6;
    int lane = tid & 63;
    int l16  = lane & 15;
    int quad = lane >> 4;
    int m0   = blockIdx.y * 64;
    int n0   = blockIdx.x * 128;
    const int K = 1024;

    f32x4 acc[4][2];
#pragma unroll
    for (int i = 0; i < 4; ++i)
#pragma unroll
        for (int j = 0; j < 2; ++j) acc[i][j] = (f32x4){0.f, 0.f, 0.f, 0.f};

    int lrow = lane >> 3;
    int gcol = ((lane & 7) ^ lrow) * 8;
    int sw   = l16 & 7;

    for (int kt = 0; kt < 16; ++kt) {
        int k0 = kt * 64;
        // A: 8 chunks (2 per wave); B: 16 chunks (4 per wave)
#pragma unroll
        for (int j = 0; j < 2; ++j) {
            int chunk = wave * 2 + j;
            int grow  = chunk * 8 + lrow;
            async_cp16(&A[(size_t)(m0 + grow) * K + k0 + gcol], &As[chunk * 512]);
        }
#pragma unroll
        for (int j = 0; j < 4; ++j) {
            int chunk = wave * 4 + j;
            int grow  = chunk * 8 + lrow;
            async_cp16(&Bt[(size_t)(n0 + grow) * K + k0 + gcol], &Bs[chunk * 512]);
        }
        __syncthreads();

#pragma unroll
        for (int kb = 0; kb < 2; ++kb) {
            bf16x8 af[4], bf[2];
#pragma unroll
            for (int i = 0; i < 4; ++i)
                af[i] = *(const bf16x8*)&As[(i * 16 + l16) * 64 +
                                            (((kb * 4 + quad) ^ sw) << 3)];
#pragma unroll
            for (int j = 0; j < 2; ++j)
                bf[j] = *(const bf16x8*)&Bs[(wave * 32 + j * 16 + l16) * 64 +
                                            (((kb * 4 + quad) ^ sw) << 3)];
#pragma unroll
            for (int i = 0; i < 4; ++i)
#pragma unroll
                for (int j = 0; j < 2; ++j)
                    acc[i][j] = __builtin_amdgcn_mfma_f32_16x16x32_bf16(af[i], bf[j],
                                                                        acc[i][j], 0, 0, 0);
        }
        __syncthreads();
    }

    int outf32 = *flag;
#pragma unroll
    for (int j = 0; j < 2; ++j) {
        int n = n0 + wave * 32 + j * 16 + l16;
        float bv = bias[n];
#pragma unroll
        for (int i = 0; i < 4; ++i)
#pragma unroll
            for (int r = 0; r < 4; ++r) {
                int m = m0 + i * 16 + quad * 4 + r;
                float v = acc[i][j][r] + bv;
                if (outf32) ((float*)out)[(size_t)m * D_DIM + n] = v;
                else        ((ushort*)out)[(size_t)m * D_DIM + n] = f2bf(v);
            }
    }
}

// ---------------------------------------------------------------------------
// Causal attention, 64-query tiles (occupancy: 1024 blocks -> 4+ blocks/CU,
// 4 waves/SIMD vs 2 for the old 128-query shape; kernel is latency-bound:
// MfmaUtil 14%, VALUBusy 31%, Occupancy 12.7% at 128q).
// Each wave owns 16 queries. S^T formulation. qt permutation balances the
// 4 co-resident blocks per CU (dispatch stride 256 = 8 y-slots): groups
// {y, y+8, y+16, y+24} get qt {y, 23-y, y, 55-y}, summing to 62 each.
// Q (pre-scaled 0.125*log2e), K: (BH,S,64) bf16.  Vt: (BH,64,S) bf16.
// ---------------------------------------------------------------------------
#define SLD 72
__global__ __launch_bounds__(256) void attn_kernel(const ushort* __restrict__ Qg,
                                                   const ushort* __restrict__ Kg,
                                                   const ushort* __restrict__ Vt,
                                                   ushort* __restrict__ attn_out) {
    __shared__ ushort Ks[64 * SLD];
    __shared__ ushort Vs[64 * SLD];
    __shared__ ushort Ss[64 * SLD];
    int tid  = threadIdx.x;
    int wave = tid >> 6;
    int lane = tid & 63;
    int l16  = lane & 15;
    int quad = lane >> 4;
    int bh   = blockIdx.x;
    int y    = blockIdx.y;
    // CU-balanced permutation over 32 q-tiles (see header comment)
    int qt   = (y < 8) ? y : (y < 16) ? (23 - y) : (y < 24) ? y : (55 - y);
    int q0   = qt * 64;

    const ushort* Qb = Qg + (size_t)bh * S_DIM * HD_DIM;
    const ushort* Kb = Kg + (size_t)bh * S_DIM * HD_DIM;
    const ushort* Vb = Vt + (size_t)bh * HD_DIM * S_DIM;

    // Q fragments (B-operand layout: n=l16=query, k=quad*8+j)
    bf16x8 qf[2];
#pragma unroll
    for (int ks = 0; ks < 2; ++ks)
        qf[ks] = *(const bf16x8*)&Qb[(size_t)(q0 + wave * 16 + l16) * HD_DIM +
                                     ks * 32 + quad * 8];

    f32x4 o[4];
#pragma unroll
    for (int i = 0; i < 4; ++i) o[i] = (f32x4){0.f, 0.f, 0.f, 0.f};
    float rsum = 0.f;             // per-lane: query l16 of this wave's 16

    int srow = tid >> 3;          // 0..31
    int scol = (tid & 7) * 8;     // 0..56

    // prefetch tile 0
    bf16x8 kr[2], vr[2];
#pragma unroll
    for (int p = 0; p < 2; ++p) {
        kr[p] = *(const bf16x8*)&Kb[(size_t)(srow + 32 * p) * HD_DIM + scol];
        vr[p] = *(const bf16x8*)&Vb[(size_t)(srow + 32 * p) * S_DIM + scol];
    }

    int ntiles = qt + 1;          // keys 0 .. qt*64+63
    for (int t = 0; t < ntiles; ++t) {
        __syncthreads();
#pragma unroll
        for (int p = 0; p < 2; ++p) {
            *(bf16x8*)&Ks[(srow + 32 * p) * SLD + scol] = kr[p];
            *(bf16x8*)&Vs[(srow + 32 * p) * SLD + scol] = vr[p];
        }
        __syncthreads();
        if (t + 1 < ntiles) {
            int k1 = (t + 1) * 64;
#pragma unroll
            for (int p = 0; p < 2; ++p) {
                kr[p] = *(const bf16x8*)&Kb[(size_t)(k1 + srow + 32 * p) * HD_DIM + scol];
                vr[p] = *(const bf16x8*)&Vb[(size_t)(srow + 32 * p) * S_DIM + k1 + scol];
            }
        }

        int k0 = t * 64;

        // ---- S^T = K Q^T from LDS ----
        f32x4 sc[4];
#pragma unroll
        for (int i = 0; i < 4; ++i) sc[i] = (f32x4){0.f, 0.f, 0.f, 0.f};
#pragma unroll
        for (int ks = 0; ks < 2; ++ks)
#pragma unroll
            for (int nb = 0; nb < 4; ++nb) {
                bf16x8 kf = *(const bf16x8*)&Ks[(nb * 16 + l16) * SLD + ks * 32 + quad * 8];
                sc[nb] = __builtin_amdgcn_mfma_f32_16x16x32_bf16(kf, qf[ks],
                                                                 sc[nb], 0, 0, 0);
            }

        // ---- causal mask (only the final tile covers the diagonal) ----
        if (t == ntiles - 1) {
            int qglob = q0 + wave * 16 + l16;
#pragma unroll
            for (int nb = 0; nb < 4; ++nb) {
                int key = k0 + nb * 16 + quad * 4;
#pragma unroll
                for (int r = 0; r < 4; ++r)
                    if (key + r > qglob) sc[nb][r] = -1e30f;
            }
        }

        // ---- exp2, per-lane row-sum, packed P stash (b64, keys contiguous) ----
#pragma unroll
        for (int nb = 0; nb < 4; ++nb) {
            ushort pk[4];
            float ps = 0.f;
#pragma unroll
            for (int r = 0; r < 4; ++r) {
                float p = __builtin_amdgcn_exp2f(sc[nb][r]);
                ps += p;
                pk[r] = f2bf(p);
            }
            rsum += ps;
            *(uint2*)&Ss[(wave * 16 + l16) * SLD + nb * 16 + quad * 4] = *(uint2*)pk;
        }

        // ---- P fragments (A layout: m=l16=query, k=keys) from LDS ----
        bf16x8 pf[2];
#pragma unroll
        for (int ks = 0; ks < 2; ++ks)
            pf[ks] = *(const bf16x8*)&Ss[(wave * 16 + l16) * SLD + ks * 32 + quad * 8];

        // ---- PV from LDS ----
#pragma unroll
        for (int ks = 0; ks < 2; ++ks)
#pragma unroll
            for (int nb = 0; nb < 4; ++nb) {
                bf16x8 vf = *(const bf16x8*)&Vs[(nb * 16 + l16) * SLD + ks * 32 + quad * 8];
                o[nb] = __builtin_amdgcn_mfma_f32_16x16x32_bf16(pf[ks], vf,
                                                                o[nb], 0, 0, 0);
            }
    }

    // full row sums: reduce over the 4 quads holding the same query l16
    rsum += __shfl_xor(rsum, 16, 64);
    rsum += __shfl_xor(rsum, 32, 64);

    // epilogue: o[nb] C-layout: col=l16=hd, row=quad*4+r=query-within-wave
    int b = bh >> 4, h = bh & 15;
    float inv[4];
#pragma unroll
    for (int r = 0; r < 4; ++r)
        inv[r] = 1.f / __shfl(rsum, quad * 4 + r, 64);
#pragma unroll
    for (int nb = 0; nb < 4; ++nb)
#pragma unroll
        for (int r = 0; r < 4; ++r) {
            int q = q0 + wave * 16 + quad * 4 + r;
            attn_out[(size_t)(b * S_DIM + q) * D_DIM + h * HD_DIM + nb * 16 + l16] =
                f2bf(o[nb][r] * inv[r]);
        }
}

// ---------------------------------------------------------------------------
extern "C" void kernel_launch(void* const* d_in, const int* in_sizes, int n_in,
                              void* d_out, int out_size, void* d_ws, size_t ws_size,
                              hipStream_t stream) {
    const void* x  = d_in[0];
    const void* Wq = d_in[1];
    const void* bq = d_in[2];
    const void* Wk = d_in[3];
    const void* bk = d_in[4];
    const void* Wv = d_in[5];
    const void* bv = d_in[6];
    const void* Wo = d_in[7];
    const void* bo = d_in[8];
    // d_in[9] = mask: exactly causal tril, handled analytically.

    char* ws = (char*)d_ws;
    const size_t MB = 1024 * 1024;
    const size_t base = 64 * 1024;
    int*    flag   = (int*)ws;
    float*  biasf  = (float*)(ws + 4096);
    ushort* xc     = (ushort*)(ws + base);                  // 8 MiB; reused as attn later
    ushort* Wqkvt  = (ushort*)(ws + base + 8  * MB);        // 6 MiB (3072x1024)
    ushort* Wot    = (ushort*)(ws + base + 14 * MB);        // 2 MiB
    ushort* Qc     = (ushort*)(ws + base + 16 * MB);        // Q,K slices (BH,S,64)
    ushort* Vtp    = (ushort*)(ws + base + 40 * MB);        // 8 MiB (BH,64,S), direct
    ushort* attn   = xc;                                    // xc dead before attn writes

    dim3 tb(256);

    detect_kernel<<<1, tb, 0, stream>>>((const ushort*)x, flag);

    dim3 pg(16, 16, 6);
    prep_kernel<<<pg, tb, 0, stream>>>(x, Wq, Wk, Wv, Wo, bq, bk, bv, bo,
                                       xc, Wqkvt, Wot, biasf, flag);

    // Fused QKV projection: (4096x1024) x (3072x1024)^T; V written transposed
    dim3 gq(3 * D_DIM / 128, (B_DIM * S_DIM) / 128);   // (24, 32)
    gemm128_kernel<<<gq, tb, 0, stream>>>(xc, Wqkvt, biasf, Qc, Vtp);

    dim3 ag(B_DIM * H_DIM, S_DIM / 64);                // (32, 32) = 1024 blocks
    attn_kernel<<<ag, tb, 0, stream>>>(Qc, Qc + (size_t)B_DIM * H_DIM * S_DIM * HD_DIM,
                                       Vtp, attn);

    dim3 go(D_DIM / 128, (B_DIM * S_DIM) / 64);        // (8, 64) = 512 blocks
    gemm64_kernel<<<go, tb, 0, stream>>>(attn, Wot, biasf + 3072, d_out, flag);
}

// Round 2
// 195.211 us; speedup vs baseline: 1.0334x; 1.0022x over previous
//
#include <hip/hip_runtime.h>
#include <hip/hip_bf16.h>

typedef __attribute__((ext_vector_type(8))) short bf16x8;
typedef __attribute__((ext_vector_type(4))) float f32x4;

#define B_DIM  2
#define S_DIM  2048
#define D_DIM  1024
#define H_DIM  16
#define HD_DIM 64

__device__ __forceinline__ float bf2f(ushort u) {
    union { unsigned int ui; float f; } c; c.ui = ((unsigned int)u) << 16; return c.f;
}
__device__ __forceinline__ ushort f2bf(float f) {
    __hip_bfloat16 h = __float2bfloat16(f);
    return *reinterpret_cast<ushort*>(&h);
}

// Async global->LDS DMA, 16 B per lane. LDS dest = wave-uniform base + lane*16.
__device__ __forceinline__ void async_cp16(const ushort* g, ushort* l) {
    __builtin_amdgcn_global_load_lds(
        (const __attribute__((address_space(1))) void*)g,
        (__attribute__((address_space(3))) void*)l, 16, 0, 0);
}

// pack two f32 -> one u32 of 2 bf16 (lo = first arg), RNE
__device__ __forceinline__ unsigned int cvt_pk_bf16(float lo, float hi) {
    unsigned int d;
    asm volatile("v_cvt_pk_bf16_f32 %0, %1, %2" : "=v"(d) : "v"(lo), "v"(hi));
    return d;
}
// after: a' = [a.lo32 | b.lo32], b' = [a.hi32 | b.hi32]
__device__ __forceinline__ void pl32swap(unsigned int& a, unsigned int& b) {
    asm volatile("v_permlane32_swap_b32 %0, %1" : "+v"(a), "+v"(b));
}
// rows of 16: a' = [a.r0 b.r0 a.r2 b.r2], b' = [a.r1 b.r1 a.r3 b.r3]
__device__ __forceinline__ void pl16swap(unsigned int& a, unsigned int& b) {
    asm volatile("v_permlane16_swap_b32 %0, %1" : "+v"(a), "+v"(b));
}

// ---------------------------------------------------------------------------
// Dtype detector: valid bf16 inputs never have exponent bits 0xFF; fp32 read
// as u16 halves hits 0xFF with p~1/256. flag=1 -> fp32 inputs, 0 -> bf16.
// ---------------------------------------------------------------------------
__global__ __launch_bounds__(256) void detect_kernel(const ushort* __restrict__ x,
                                                     int* __restrict__ flag) {
    __shared__ int any;
    int tid = threadIdx.x;
    if (tid == 0) any = 0;
    __syncthreads();
    int cnt = 0;
    for (int j = 0; j < 64; ++j) {
        ushort u = x[tid * 64 + j];
        if (((u >> 7) & 0xFF) == 0xFF) cnt++;
    }
    if (cnt) atomicOr(&any, 1);
    __syncthreads();
    if (tid == 0) *flag = any ? 1 : 0;
}

// ---------------------------------------------------------------------------
// Merged prep: grid (16,16,6).
//   z in 0..3 : convert + transpose weight z (Q/K/V -> Wqkvt slices, O -> Wot)
//   z == 4   : canonicalize x -> bf16 (4M elems)
//   z == 5   : biases -> fp32 (first 16 blocks)
// ---------------------------------------------------------------------------
__global__ __launch_bounds__(256) void prep_kernel(const void* __restrict__ x,
                                                   const void* __restrict__ Wq,
                                                   const void* __restrict__ Wk,
                                                   const void* __restrict__ Wv,
                                                   const void* __restrict__ Wo,
                                                   const void* __restrict__ bq,
                                                   const void* __restrict__ bk,
                                                   const void* __restrict__ bv,
                                                   const void* __restrict__ bo,
                                                   ushort* __restrict__ xc,
                                                   ushort* __restrict__ Wqkvt,
                                                   ushort* __restrict__ Wot,
                                                   float* __restrict__ biasf,
                                                   const int* __restrict__ flag) {
    int tid = threadIdx.x;
    int z = blockIdx.z;
    bool isf32 = (*flag != 0);

    if (z == 4) {
        int t = (blockIdx.y * 16 + blockIdx.x) * 256 + tid;   // 0..65535
#pragma unroll
        for (int c = 0; c < 8; ++c) {
            int i = t + c * 65536;                            // elem8 index
            if (isf32) {
                const float* s = (const float*)x;
                f32x4 a = *(const f32x4*)&s[(size_t)i * 8];
                f32x4 b = *(const f32x4*)&s[(size_t)i * 8 + 4];
                bf16x8 o;
                o[0] = f2bf(a.x); o[1] = f2bf(a.y); o[2] = f2bf(a.z); o[3] = f2bf(a.w);
                o[4] = f2bf(b.x); o[5] = f2bf(b.y); o[6] = f2bf(b.z); o[7] = f2bf(b.w);
                *(bf16x8*)&xc[(size_t)i * 8] = o;
            } else {
                *(bf16x8*)&xc[(size_t)i * 8] =
                    *(const bf16x8*)&((const ushort*)x)[(size_t)i * 8];
            }
        }
        return;
    }
    if (z == 5) {
        int bid = blockIdx.y * 16 + blockIdx.x;
        if (bid >= 16) return;
        int i = bid * 256 + tid;                              // 0..4095
        int w = i >> 10, j = i & 1023;
        const void* s = (w == 0) ? bq : (w == 1) ? bk : (w == 2) ? bv : bo;
        biasf[i] = isf32 ? ((const float*)s)[j] : bf2f(((const ushort*)s)[j]);
        return;
    }

    // weight transpose
    __shared__ ushort tile[64][72];
    const void* src = (z == 0) ? Wq : (z == 1) ? Wk : (z == 2) ? Wv : Wo;
    ushort* dst = (z < 3) ? (Wqkvt + (size_t)z * D_DIM * D_DIM) : Wot;
    int r0 = blockIdx.y * 64, c0 = blockIdx.x * 64;
#pragma unroll
    for (int p = 0; p < 2; ++p) {
        int r = p * 32 + (tid >> 3);
        int c = (tid & 7) * 8;
        if (isf32) {
            const float* s = (const float*)src;
            f32x4 a = *(const f32x4*)&s[(size_t)(r0 + r) * D_DIM + c0 + c];
            f32x4 b = *(const f32x4*)&s[(size_t)(r0 + r) * D_DIM + c0 + c + 4];
            tile[r][c + 0] = f2bf(a.x); tile[r][c + 1] = f2bf(a.y);
            tile[r][c + 2] = f2bf(a.z); tile[r][c + 3] = f2bf(a.w);
            tile[r][c + 4] = f2bf(b.x); tile[r][c + 5] = f2bf(b.y);
            tile[r][c + 6] = f2bf(b.z); tile[r][c + 7] = f2bf(b.w);
        } else {
            *(bf16x8*)&tile[r][c] =
                *(const bf16x8*)&((const ushort*)src)[(size_t)(r0 + r) * D_DIM + c0 + c];
        }
    }
    __syncthreads();
#pragma unroll
    for (int p = 0; p < 2; ++p) {
        int n  = p * 32 + (tid >> 3);
        int cc = (tid & 7) * 8;
        bf16x8 v;
#pragma unroll
        for (int e = 0; e < 8; ++e) v[e] = (short)tile[cc + e][n];
        *(bf16x8*)&dst[(size_t)(c0 + n) * D_DIM + r0 + cc] = v;
    }
}

// ---------------------------------------------------------------------------
// Fused QKV GEMM: 128x128 tile, BK=64, global_load_lds(16B), XOR swizzle
// (0 bank conflicts). Ncols=3072. Q slice pre-scaled by 0.125*log2(e);
// Q/K slices -> (BH,S,64) bf16; V slice -> TRANSPOSED (BH,64,S) bf16 directly
// (packed 8B stores; 16 rows x 32B per wave-store: L2-merged).
// ---------------------------------------------------------------------------
__global__ __launch_bounds__(256) void gemm128_kernel(const ushort* __restrict__ A,
                                                      const ushort* __restrict__ Bt,
                                                      const float* __restrict__ bias,
                                                      ushort* __restrict__ qkout,
                                                      ushort* __restrict__ vtout) {
    __shared__ ushort As[128 * 64];   // 16 KiB, unpadded
    __shared__ ushort Bs[128 * 64];
    int tid  = threadIdx.x;
    int wave = tid >> 6;
    int lane = tid & 63;
    int l16  = lane & 15;
    int quad = lane >> 4;
    int m0   = blockIdx.y * 128;
    int n0   = blockIdx.x * 128;
    int wm   = wave >> 1;
    int wn   = wave & 1;
    const int K = 1024;

    f32x4 acc[4][4];
#pragma unroll
    for (int i = 0; i < 4; ++i)
#pragma unroll
        for (int j = 0; j < 4; ++j) acc[i][j] = (f32x4){0.f, 0.f, 0.f, 0.f};

    int lrow = lane >> 3;                         // 0..7 row within chunk
    int gcol = ((lane & 7) ^ lrow) * 8;           // swizzled column (elems)
    int sw   = l16 & 7;                           // fragment-read swizzle

    for (int kt = 0; kt < 16; ++kt) {
        int k0 = kt * 64;
#pragma unroll
        for (int j = 0; j < 4; ++j) {
            int chunk = wave * 4 + j;             // 0..15; 8 rows each
            int grow  = chunk * 8 + lrow;
            async_cp16(&A[(size_t)(m0 + grow) * K + k0 + gcol], &As[chunk * 512]);
            async_cp16(&Bt[(size_t)(n0 + grow) * K + k0 + gcol], &Bs[chunk * 512]);
        }
        __syncthreads();

#pragma unroll
        for (int kb = 0; kb < 2; ++kb) {
            bf16x8 af[4], bf[4];
#pragma unroll
            for (int i = 0; i < 4; ++i)
                af[i] = *(const bf16x8*)&As[(wm * 64 + i * 16 + l16) * 64 +
                                            (((kb * 4 + quad) ^ sw) << 3)];
#pragma unroll
            for (int j = 0; j < 4; ++j)
                bf[j] = *(const bf16x8*)&Bs[(wn * 64 + j * 16 + l16) * 64 +
                                            (((kb * 4 + quad) ^ sw) << 3)];
#pragma unroll
            for (int i = 0; i < 4; ++i)
#pragma unroll
                for (int j = 0; j < 4; ++j)
                    acc[i][j] = __builtin_amdgcn_mfma_f32_16x16x32_bf16(af[i], bf[j],
                                                                        acc[i][j], 0, 0, 0);
        }
        __syncthreads();
    }

    const size_t TSZ = (size_t)B_DIM * H_DIM * S_DIM * HD_DIM;   // 4 Mi elems
#pragma unroll
    for (int j = 0; j < 4; ++j) {
        int n = n0 + wn * 64 + j * 16 + l16;        // C/D col = lane&15
        float bv = bias[n];
        int which = n >> 10;                        // 0=Q 1=K 2=V
        int n1 = n & 1023;
        int h = n1 >> 6, hd = n1 & 63;
#pragma unroll
        for (int i = 0; i < 4; ++i) {
            int mb = m0 + wm * 64 + i * 16 + quad * 4;     // row base (quad*4)
            int b = mb >> 11, s = mb & (S_DIM - 1);
            float v4[4];
#pragma unroll
            for (int r = 0; r < 4; ++r) v4[r] = acc[i][j][r] + bv;
            if (which == 2) {
                // V -> transposed (BH,64,S): 4 consecutive s, packed 8B store
                ushort pk[4];
#pragma unroll
                for (int r = 0; r < 4; ++r) pk[r] = f2bf(v4[r]);
                *(uint2*)&vtout[(((size_t)(b * H_DIM + h) * HD_DIM + hd)) * S_DIM + s] =
                    *(uint2*)pk;
            } else {
#pragma unroll
                for (int r = 0; r < 4; ++r) {
                    float v = v4[r];
                    // fold softmax scale AND log2(e) into Q (attn uses exp2)
                    if (which == 0) v *= 0.18033688011f;   // 0.125 * log2(e)
                    qkout[which * TSZ +
                          ((((size_t)(b * H_DIM + h)) * S_DIM + s + r) << 6) + hd] = f2bf(v);
                }
            }
        }
    }
}

// ---------------------------------------------------------------------------
// O-projection GEMM: 64x128 tile (M x N), BK=64, same staging/swizzle.
// Grid (8, 64) = 512 blocks -> 2 blocks/CU (vs 1 for the 128x128 shape):
// co-resident block overlaps the barrier's vmcnt drain. 4 waves side-by-side
// in N; per wave acc = 4(m) x 2(n) frags.
// out: bf16 or fp32 per *flag, row-major M x 1024.
// ---------------------------------------------------------------------------
__global__ __launch_bounds__(256) void gemm64_kernel(const ushort* __restrict__ A,
                                                     const ushort* __restrict__ Bt,
                                                     const float* __restrict__ bias,
                                                     void* __restrict__ out,
                                                     const int* __restrict__ flag) {
    __shared__ ushort As[64 * 64];    // 8 KiB
    __shared__ ushort Bs[128 * 64];   // 16 KiB
    int tid  = threadIdx.x;
    int wave = tid >> 6;
    int lane = tid & 63;
    int l16  = lane & 15;
    int quad = lane >> 4;
    int m0   = blockIdx.y * 64;
    int n0   = blockIdx.x * 128;
    const int K = 1024;

    f32x4 acc[4][2];
#pragma unroll
    for (int i = 0; i < 4; ++i)
#pragma unroll
        for (int j = 0; j < 2; ++j) acc[i][j] = (f32x4){0.f, 0.f, 0.f, 0.f};

    int lrow = lane >> 3;
    int gcol = ((lane & 7) ^ lrow) * 8;
    int sw   = l16 & 7;

    for (int kt = 0; kt < 16; ++kt) {
        int k0 = kt * 64;
        // A: 8 chunks (2 per wave); B: 16 chunks (4 per wave)
#pragma unroll
        for (int j = 0; j < 2; ++j) {
            int chunk = wave * 2 + j;
            int grow  = chunk * 8 + lrow;
            async_cp16(&A[(size_t)(m0 + grow) * K + k0 + gcol], &As[chunk * 512]);
        }
#pragma unroll
        for (int j = 0; j < 4; ++j) {
            int chunk = wave * 4 + j;
            int grow  = chunk * 8 + lrow;
            async_cp16(&Bt[(size_t)(n0 + grow) * K + k0 + gcol], &Bs[chunk * 512]);
        }
        __syncthreads();

#pragma unroll
        for (int kb = 0; kb < 2; ++kb) {
            bf16x8 af[4], bf[2];
#pragma unroll
            for (int i = 0; i < 4; ++i)
                af[i] = *(const bf16x8*)&As[(i * 16 + l16) * 64 +
                                            (((kb * 4 + quad) ^ sw) << 3)];
#pragma unroll
            for (int j = 0; j < 2; ++j)
                bf[j] = *(const bf16x8*)&Bs[(wave * 32 + j * 16 + l16) * 64 +
                                            (((kb * 4 + quad) ^ sw) << 3)];
#pragma unroll
            for (int i = 0; i < 4; ++i)
#pragma unroll
                for (int j = 0; j < 2; ++j)
                    acc[i][j] = __builtin_amdgcn_mfma_f32_16x16x32_bf16(af[i], bf[j],
                                                                        acc[i][j], 0, 0, 0);
        }
        __syncthreads();
    }

    int outf32 = *flag;
#pragma unroll
    for (int j = 0; j < 2; ++j) {
        int n = n0 + wave * 32 + j * 16 + l16;
        float bv = bias[n];
#pragma unroll
        for (int i = 0; i < 4; ++i)
#pragma unroll
            for (int r = 0; r < 4; ++r) {
                int m = m0 + i * 16 + quad * 4 + r;
                float v = acc[i][j][r] + bv;
                if (outf32) ((float*)out)[(size_t)m * D_DIM + n] = v;
                else        ((ushort*)out)[(size_t)m * D_DIM + n] = f2bf(v);
            }
    }
}

// ---------------------------------------------------------------------------
// Causal attention, 64-query tiles. v2: latency-bound fixes.
//  - K/V staged via async global_load_lds into XOR-swizzled double buffers
//    (one __syncthreads per tile, no ds_writes, no reg prefetch).
//  - P transpose (S^T C-layout -> PV A-fragments) fully in-register:
//    8x v_cvt_pk_bf16_f32 + 4x permlane32_swap + 4x permlane16_swap
//    per tile. No Ss LDS buffer, no mid-tile lgkmcnt(0) round-trip.
//  - V fragments read right after QK^T (overlap the exp2 VALU chain).
//  - s_setprio(1) around MFMA clusters.
// Each wave owns 16 queries. qt permutation balances per-CU work.
// Q (pre-scaled 0.125*log2e), K: (BH,S,64) bf16.  Vt: (BH,64,S) bf16.
// ---------------------------------------------------------------------------
__global__ __launch_bounds__(256, 4) void attn_kernel(const ushort* __restrict__ Qg,
                                                      const ushort* __restrict__ Kg,
                                                      const ushort* __restrict__ Vt,
                                                      ushort* __restrict__ attn_out) {
    __shared__ ushort Ks[2][64 * 64];   // 16 KiB (double buffer)
    __shared__ ushort Vs[2][64 * 64];   // 16 KiB
    int tid  = threadIdx.x;
    int wave = tid >> 6;
    int lane = tid & 63;
    int l16  = lane & 15;
    int quad = lane >> 4;
    int bh   = blockIdx.x;
    int y    = blockIdx.y;
    // CU-balanced permutation over 32 q-tiles
    int qt   = (y < 8) ? y : (y < 16) ? (23 - y) : (y < 24) ? y : (55 - y);
    int q0   = qt * 64;

    const ushort* Qb = Qg + (size_t)bh * S_DIM * HD_DIM;
    const ushort* Kb = Kg + (size_t)bh * S_DIM * HD_DIM;
    const ushort* Vb = Vt + (size_t)bh * HD_DIM * S_DIM;

    // Q fragments (B-operand layout: n=l16=query, k=quad*8+j)
    bf16x8 qf[2];
#pragma unroll
    for (int ks = 0; ks < 2; ++ks)
        qf[ks] = *(const bf16x8*)&Qb[(size_t)(q0 + wave * 16 + l16) * HD_DIM +
                                     ks * 32 + quad * 8];

    f32x4 o[4];
#pragma unroll
    for (int i = 0; i < 4; ++i) o[i] = (f32x4){0.f, 0.f, 0.f, 0.f};
    float rsum = 0.f;             // per-lane: query l16 of this wave's 16

    int lrow = lane >> 3;                 // staging row within 8-row chunk
    int gcol = ((lane & 7) ^ lrow) * 8;   // swizzled source column (elems)
    int sw   = l16 & 7;                   // fragment-read swizzle

    // stage tile 0 -> buf 0 (2 cp16 K + 2 cp16 V per thread)
#pragma unroll
    for (int j = 0; j < 2; ++j) {
        int chunk = wave * 2 + j;
        int grow  = chunk * 8 + lrow;
        async_cp16(&Kb[(size_t)grow * HD_DIM + gcol], &Ks[0][chunk * 512]);
        async_cp16(&Vb[(size_t)grow * S_DIM + gcol], &Vs[0][chunk * 512]);
    }

    int ntiles = qt + 1;          // keys 0 .. qt*64+63
    int p = 0;
    for (int t = 0; t < ntiles; ++t) {
        // implicit s_waitcnt vmcnt(0) lgkmcnt(0) + barrier: tile t visible,
        // and all waves done reading buf p^1 (their tile t-1 compute).
        __syncthreads();
        if (t + 1 < ntiles) {
            int k1 = (t + 1) * 64;
#pragma unroll
            for (int j = 0; j < 2; ++j) {
                int chunk = wave * 2 + j;
                int grow  = chunk * 8 + lrow;
                async_cp16(&Kb[(size_t)(k1 + grow) * HD_DIM + gcol],
                           &Ks[p ^ 1][chunk * 512]);
                async_cp16(&Vb[(size_t)grow * S_DIM + k1 + gcol],
                           &Vs[p ^ 1][chunk * 512]);
            }
        }
        int k0 = t * 64;

        // ---- S^T = K Q^T from LDS ----
        f32x4 sc[4];
#pragma unroll
        for (int i = 0; i < 4; ++i) sc[i] = (f32x4){0.f, 0.f, 0.f, 0.f};
        __builtin_amdgcn_s_setprio(1);
#pragma unroll
        for (int ks = 0; ks < 2; ++ks)
#pragma unroll
            for (int nb = 0; nb < 4; ++nb) {
                bf16x8 kf = *(const bf16x8*)&Ks[p][(nb * 16 + l16) * 64 +
                                                   (((ks * 4 + quad) ^ sw) << 3)];
                sc[nb] = __builtin_amdgcn_mfma_f32_16x16x32_bf16(kf, qf[ks],
                                                                 sc[nb], 0, 0, 0);
            }
        __builtin_amdgcn_s_setprio(0);

        // ---- hoist V fragment reads (overlap softmax VALU chain) ----
        bf16x8 vf[2][4];
#pragma unroll
        for (int ks = 0; ks < 2; ++ks)
#pragma unroll
            for (int nb = 0; nb < 4; ++nb)
                vf[ks][nb] = *(const bf16x8*)&Vs[p][(nb * 16 + l16) * 64 +
                                                    (((ks * 4 + quad) ^ sw) << 3)];

        // ---- causal mask (only the final tile covers the diagonal) ----
        if (t == ntiles - 1) {
            int qglob = q0 + wave * 16 + l16;
#pragma unroll
            for (int nb = 0; nb < 4; ++nb) {
                int key = k0 + nb * 16 + quad * 4;
#pragma unroll
                for (int r = 0; r < 4; ++r)
                    if (key + r > qglob) sc[nb][r] = -1e30f;
            }
        }

        // ---- exp2 + row-sum + pack to bf16 pairs ----
        // W[nb][pp] holds keys (nb*16 + quad*4 + 2pp, +1) for query l16
        unsigned int W[4][2];
        float psn[4];
#pragma unroll
        for (int nb = 0; nb < 4; ++nb) {
            float pv[4];
#pragma unroll
            for (int r = 0; r < 4; ++r) pv[r] = __builtin_amdgcn_exp2f(sc[nb][r]);
            psn[nb] = (pv[0] + pv[1]) + (pv[2] + pv[3]);
            W[nb][0] = cvt_pk_bf16(pv[0], pv[1]);
            W[nb][1] = cvt_pk_bf16(pv[2], pv[3]);
        }
        rsum += (psn[0] + psn[1]) + (psn[2] + psn[3]);

        // ---- in-register quad transpose: C-layout -> A-fragment layout ----
        // target word n[ks][jj] = keys (ks*32 + quad*8 + 2jj, +1):
        //   source lane quad_s = 2(quad&1)+(jj>>1), word W[2ks+(quad>>1)][jj&1]
        // pl32swap(W0,W1): W0=[Q01.m0|Q01.m1@Q23], W1=[Q23.m0@Q01|Q23.m1]
        // pl16swap(W0,W1): W0=[src-A word per pos], W1=[src-B word per pos]
#pragma unroll
        for (int pp = 0; pp < 2; ++pp) {
            pl32swap(W[0][pp], W[1][pp]);
            pl32swap(W[2][pp], W[3][pp]);
            pl16swap(W[0][pp], W[1][pp]);
            pl16swap(W[2][pp], W[3][pp]);
        }
        bf16x8 pf[2];
        {
            union { unsigned int u[4]; bf16x8 v; } c0, c1;
            c0.u[0] = W[0][0]; c0.u[1] = W[0][1];   // n[0][0], n[0][1]
            c0.u[2] = W[1][0]; c0.u[3] = W[1][1];   // n[0][2], n[0][3]
            c1.u[0] = W[2][0]; c1.u[1] = W[2][1];   // n[1][0], n[1][1]
            c1.u[2] = W[3][0]; c1.u[3] = W[3][1];   // n[1][2], n[1][3]
            pf[0] = c0.v; pf[1] = c1.v;
        }

        // ---- PV (V frags already in registers) ----
        __builtin_amdgcn_s_setprio(1);
#pragma unroll
        for (int ks = 0; ks < 2; ++ks)
#pragma unroll
            for (int nb = 0; nb < 4; ++nb)
                o[nb] = __builtin_amdgcn_mfma_f32_16x16x32_bf16(pf[ks], vf[ks][nb],
                                                                o[nb], 0, 0, 0);
        __builtin_amdgcn_s_setprio(0);
        p ^= 1;
    }

    // full row sums: reduce over the 4 quads holding the same query l16
    rsum += __shfl_xor(rsum, 16, 64);
    rsum += __shfl_xor(rsum, 32, 64);

    // epilogue: o[nb] C-layout: col=l16=hd, row=quad*4+r=query-within-wave
    int b = bh >> 4, h = bh & 15;
    float inv[4];
#pragma unroll
    for (int r = 0; r < 4; ++r)
        inv[r] = 1.f / __shfl(rsum, quad * 4 + r, 64);
#pragma unroll
    for (int nb = 0; nb < 4; ++nb)
#pragma unroll
        for (int r = 0; r < 4; ++r) {
            int q = q0 + wave * 16 + quad * 4 + r;
            attn_out[(size_t)(b * S_DIM + q) * D_DIM + h * HD_DIM + nb * 16 + l16] =
                f2bf(o[nb][r] * inv[r]);
        }
}

// ---------------------------------------------------------------------------
extern "C" void kernel_launch(void* const* d_in, const int* in_sizes, int n_in,
                              void* d_out, int out_size, void* d_ws, size_t ws_size,
                              hipStream_t stream) {
    const void* x  = d_in[0];
    const void* Wq = d_in[1];
    const void* bq = d_in[2];
    const void* Wk = d_in[3];
    const void* bk = d_in[4];
    const void* Wv = d_in[5];
    const void* bv = d_in[6];
    const void* Wo = d_in[7];
    const void* bo = d_in[8];
    // d_in[9] = mask: exactly causal tril, handled analytically.

    char* ws = (char*)d_ws;
    const size_t MB = 1024 * 1024;
    const size_t base = 64 * 1024;
    int*    flag   = (int*)ws;
    float*  biasf  = (float*)(ws + 4096);
    ushort* xc     = (ushort*)(ws + base);                  // 8 MiB; reused as attn later
    ushort* Wqkvt  = (ushort*)(ws + base + 8  * MB);        // 6 MiB (3072x1024)
    ushort* Wot    = (ushort*)(ws + base + 14 * MB);        // 2 MiB
    ushort* Qc     = (ushort*)(ws + base + 16 * MB);        // Q,K slices (BH,S,64)
    ushort* Vtp    = (ushort*)(ws + base + 40 * MB);        // 8 MiB (BH,64,S), direct
    ushort* attn   = xc;                                    // xc dead before attn writes

    dim3 tb(256);

    detect_kernel<<<1, tb, 0, stream>>>((const ushort*)x, flag);

    dim3 pg(16, 16, 6);
    prep_kernel<<<pg, tb, 0, stream>>>(x, Wq, Wk, Wv, Wo, bq, bk, bv, bo,
                                       xc, Wqkvt, Wot, biasf, flag);

    // Fused QKV projection: (4096x1024) x (3072x1024)^T; V written transposed
    dim3 gq(3 * D_DIM / 128, (B_DIM * S_DIM) / 128);   // (24, 32)
    gemm128_kernel<<<gq, tb, 0, stream>>>(xc, Wqkvt, biasf, Qc, Vtp);

    dim3 ag(B_DIM * H_DIM, S_DIM / 64);                // (32, 32) = 1024 blocks
    attn_kernel<<<ag, tb, 0, stream>>>(Qc, Qc + (size_t)B_DIM * H_DIM * S_DIM * HD_DIM,
                                       Vtp, attn);

    dim3 go(D_DIM / 128, (B_DIM * S_DIM) / 64);        // (8, 64) = 512 blocks
    gemm64_kernel<<<go, tb, 0, stream>>>(attn, Wot, biasf + 3072, d_out, flag);
}

// Round 3
// 194.758 us; speedup vs baseline: 1.0358x; 1.0023x over previous
//
#include <hip/hip_runtime.h>
#include <hip/hip_bf16.h>

typedef __attribute__((ext_vector_type(8))) short bf16x8;
typedef __attribute__((ext_vector_type(4))) float f32x4;
typedef __attribute__((ext_vector_type(16))) float f32x16;

#define B_DIM  2
#define S_DIM  2048
#define D_DIM  1024
#define H_DIM  16
#define HD_DIM 64

__device__ __forceinline__ float bf2f(ushort u) {
    union { unsigned int ui; float f; } c; c.ui = ((unsigned int)u) << 16; return c.f;
}
__device__ __forceinline__ ushort f2bf(float f) {
    __hip_bfloat16 h = __float2bfloat16(f);
    return *reinterpret_cast<ushort*>(&h);
}

// Async global->LDS DMA, 16 B per lane. LDS dest = wave-uniform base + lane*16.
__device__ __forceinline__ void async_cp16(const ushort* g, ushort* l) {
    __builtin_amdgcn_global_load_lds(
        (const __attribute__((address_space(1))) void*)g,
        (__attribute__((address_space(3))) void*)l, 16, 0, 0);
}

// pack two f32 -> one u32 of 2 bf16 (lo = first arg), RNE
__device__ __forceinline__ unsigned int cvt_pk_bf16(float lo, float hi) {
    unsigned int d;
    asm volatile("v_cvt_pk_bf16_f32 %0, %1, %2" : "=v"(d) : "v"(lo), "v"(hi));
    return d;
}
// after: a' = [a.lo32 | b.lo32], b' = [a.hi32 | b.hi32]
__device__ __forceinline__ void pl32swap(unsigned int& a, unsigned int& b) {
    asm volatile("v_permlane32_swap_b32 %0, %1" : "+v"(a), "+v"(b));
}

// ---------------------------------------------------------------------------
// Dtype detector: valid bf16 inputs never have exponent bits 0xFF; fp32 read
// as u16 halves hits 0xFF with p~1/256. flag=1 -> fp32 inputs, 0 -> bf16.
// ---------------------------------------------------------------------------
__global__ __launch_bounds__(256) void detect_kernel(const ushort* __restrict__ x,
                                                     int* __restrict__ flag) {
    __shared__ int any;
    int tid = threadIdx.x;
    if (tid == 0) any = 0;
    __syncthreads();
    int cnt = 0;
    for (int j = 0; j < 64; ++j) {
        ushort u = x[tid * 64 + j];
        if (((u >> 7) & 0xFF) == 0xFF) cnt++;
    }
    if (cnt) atomicOr(&any, 1);
    __syncthreads();
    if (tid == 0) *flag = any ? 1 : 0;
}

// ---------------------------------------------------------------------------
// Merged prep: grid (16,16,6).
//   z in 0..3 : convert + transpose weight z (Q/K/V -> Wqkvt slices, O -> Wot)
//   z == 4   : canonicalize x -> bf16 (4M elems)
//   z == 5   : biases -> fp32 (first 16 blocks)
// ---------------------------------------------------------------------------
__global__ __launch_bounds__(256) void prep_kernel(const void* __restrict__ x,
                                                   const void* __restrict__ Wq,
                                                   const void* __restrict__ Wk,
                                                   const void* __restrict__ Wv,
                                                   const void* __restrict__ Wo,
                                                   const void* __restrict__ bq,
                                                   const void* __restrict__ bk,
                                                   const void* __restrict__ bv,
                                                   const void* __restrict__ bo,
                                                   ushort* __restrict__ xc,
                                                   ushort* __restrict__ Wqkvt,
                                                   ushort* __restrict__ Wot,
                                                   float* __restrict__ biasf,
                                                   const int* __restrict__ flag) {
    int tid = threadIdx.x;
    int z = blockIdx.z;
    bool isf32 = (*flag != 0);

    if (z == 4) {
        int t = (blockIdx.y * 16 + blockIdx.x) * 256 + tid;   // 0..65535
#pragma unroll
        for (int c = 0; c < 8; ++c) {
            int i = t + c * 65536;                            // elem8 index
            if (isf32) {
                const float* s = (const float*)x;
                f32x4 a = *(const f32x4*)&s[(size_t)i * 8];
                f32x4 b = *(const f32x4*)&s[(size_t)i * 8 + 4];
                bf16x8 o;
                o[0] = f2bf(a.x); o[1] = f2bf(a.y); o[2] = f2bf(a.z); o[3] = f2bf(a.w);
                o[4] = f2bf(b.x); o[5] = f2bf(b.y); o[6] = f2bf(b.z); o[7] = f2bf(b.w);
                *(bf16x8*)&xc[(size_t)i * 8] = o;
            } else {
                *(bf16x8*)&xc[(size_t)i * 8] =
                    *(const bf16x8*)&((const ushort*)x)[(size_t)i * 8];
            }
        }
        return;
    }
    if (z == 5) {
        int bid = blockIdx.y * 16 + blockIdx.x;
        if (bid >= 16) return;
        int i = bid * 256 + tid;                              // 0..4095
        int w = i >> 10, j = i & 1023;
        const void* s = (w == 0) ? bq : (w == 1) ? bk : (w == 2) ? bv : bo;
        biasf[i] = isf32 ? ((const float*)s)[j] : bf2f(((const ushort*)s)[j]);
        return;
    }

    // weight transpose
    __shared__ ushort tile[64][72];
    const void* src = (z == 0) ? Wq : (z == 1) ? Wk : (z == 2) ? Wv : Wo;
    ushort* dst = (z < 3) ? (Wqkvt + (size_t)z * D_DIM * D_DIM) : Wot;
    int r0 = blockIdx.y * 64, c0 = blockIdx.x * 64;
#pragma unroll
    for (int p = 0; p < 2; ++p) {
        int r = p * 32 + (tid >> 3);
        int c = (tid & 7) * 8;
        if (isf32) {
            const float* s = (const float*)src;
            f32x4 a = *(const f32x4*)&s[(size_t)(r0 + r) * D_DIM + c0 + c];
            f32x4 b = *(const f32x4*)&s[(size_t)(r0 + r) * D_DIM + c0 + c + 4];
            tile[r][c + 0] = f2bf(a.x); tile[r][c + 1] = f2bf(a.y);
            tile[r][c + 2] = f2bf(a.z); tile[r][c + 3] = f2bf(a.w);
            tile[r][c + 4] = f2bf(b.x); tile[r][c + 5] = f2bf(b.y);
            tile[r][c + 6] = f2bf(b.z); tile[r][c + 7] = f2bf(b.w);
        } else {
            *(bf16x8*)&tile[r][c] =
                *(const bf16x8*)&((const ushort*)src)[(size_t)(r0 + r) * D_DIM + c0 + c];
        }
    }
    __syncthreads();
#pragma unroll
    for (int p = 0; p < 2; ++p) {
        int n  = p * 32 + (tid >> 3);
        int cc = (tid & 7) * 8;
        bf16x8 v;
#pragma unroll
        for (int e = 0; e < 8; ++e) v[e] = (short)tile[cc + e][n];
        *(bf16x8*)&dst[(size_t)(c0 + n) * D_DIM + r0 + cc] = v;
    }
}

// ---------------------------------------------------------------------------
// Fused QKV GEMM: 128x128 tile, BK=64, global_load_lds(16B), XOR swizzle
// (0 bank conflicts). Ncols=3072. Q slice pre-scaled by 0.125*log2(e);
// Q/K slices -> (BH,S,64) bf16; V slice -> TRANSPOSED (BH,64,S) bf16 directly
// (packed 8B stores; 16 rows x 32B per wave-store: L2-merged).
// ---------------------------------------------------------------------------
__global__ __launch_bounds__(256) void gemm128_kernel(const ushort* __restrict__ A,
                                                      const ushort* __restrict__ Bt,
                                                      const float* __restrict__ bias,
                                                      ushort* __restrict__ qkout,
                                                      ushort* __restrict__ vtout) {
    __shared__ ushort As[128 * 64];   // 16 KiB, unpadded
    __shared__ ushort Bs[128 * 64];
    int tid  = threadIdx.x;
    int wave = tid >> 6;
    int lane = tid & 63;
    int l16  = lane & 15;
    int quad = lane >> 4;
    int m0   = blockIdx.y * 128;
    int n0   = blockIdx.x * 128;
    int wm   = wave >> 1;
    int wn   = wave & 1;
    const int K = 1024;

    f32x4 acc[4][4];
#pragma unroll
    for (int i = 0; i < 4; ++i)
#pragma unroll
        for (int j = 0; j < 4; ++j) acc[i][j] = (f32x4){0.f, 0.f, 0.f, 0.f};

    int lrow = lane >> 3;                         // 0..7 row within chunk
    int gcol = ((lane & 7) ^ lrow) * 8;           // swizzled column (elems)
    int sw   = l16 & 7;                           // fragment-read swizzle

    for (int kt = 0; kt < 16; ++kt) {
        int k0 = kt * 64;
#pragma unroll
        for (int j = 0; j < 4; ++j) {
            int chunk = wave * 4 + j;             // 0..15; 8 rows each
            int grow  = chunk * 8 + lrow;
            async_cp16(&A[(size_t)(m0 + grow) * K + k0 + gcol], &As[chunk * 512]);
            async_cp16(&Bt[(size_t)(n0 + grow) * K + k0 + gcol], &Bs[chunk * 512]);
        }
        __syncthreads();

#pragma unroll
        for (int kb = 0; kb < 2; ++kb) {
            bf16x8 af[4], bf[4];
#pragma unroll
            for (int i = 0; i < 4; ++i)
                af[i] = *(const bf16x8*)&As[(wm * 64 + i * 16 + l16) * 64 +
                                            (((kb * 4 + quad) ^ sw) << 3)];
#pragma unroll
            for (int j = 0; j < 4; ++j)
                bf[j] = *(const bf16x8*)&Bs[(wn * 64 + j * 16 + l16) * 64 +
                                            (((kb * 4 + quad) ^ sw) << 3)];
#pragma unroll
            for (int i = 0; i < 4; ++i)
#pragma unroll
                for (int j = 0; j < 4; ++j)
                    acc[i][j] = __builtin_amdgcn_mfma_f32_16x16x32_bf16(af[i], bf[j],
                                                                        acc[i][j], 0, 0, 0);
        }
        __syncthreads();
    }

    const size_t TSZ = (size_t)B_DIM * H_DIM * S_DIM * HD_DIM;   // 4 Mi elems
#pragma unroll
    for (int j = 0; j < 4; ++j) {
        int n = n0 + wn * 64 + j * 16 + l16;        // C/D col = lane&15
        float bv = bias[n];
        int which = n >> 10;                        // 0=Q 1=K 2=V
        int n1 = n & 1023;
        int h = n1 >> 6, hd = n1 & 63;
#pragma unroll
        for (int i = 0; i < 4; ++i) {
            int mb = m0 + wm * 64 + i * 16 + quad * 4;     // row base (quad*4)
            int b = mb >> 11, s = mb & (S_DIM - 1);
            float v4[4];
#pragma unroll
            for (int r = 0; r < 4; ++r) v4[r] = acc[i][j][r] + bv;
            if (which == 2) {
                // V -> transposed (BH,64,S): 4 consecutive s, packed 8B store
                ushort pk[4];
#pragma unroll
                for (int r = 0; r < 4; ++r) pk[r] = f2bf(v4[r]);
                *(uint2*)&vtout[(((size_t)(b * H_DIM + h) * HD_DIM + hd)) * S_DIM + s] =
                    *(uint2*)pk;
            } else {
#pragma unroll
                for (int r = 0; r < 4; ++r) {
                    float v = v4[r];
                    // fold softmax scale AND log2(e) into Q (attn uses exp2)
                    if (which == 0) v *= 0.18033688011f;   // 0.125 * log2(e)
                    qkout[which * TSZ +
                          ((((size_t)(b * H_DIM + h)) * S_DIM + s + r) << 6) + hd] = f2bf(v);
                }
            }
        }
    }
}

// ---------------------------------------------------------------------------
// O-projection GEMM: 64x128 tile (M x N), BK=64, same staging/swizzle.
// ---------------------------------------------------------------------------
__global__ __launch_bounds__(256) void gemm64_kernel(const ushort* __restrict__ A,
                                                     const ushort* __restrict__ Bt,
                                                     const float* __restrict__ bias,
                                                     void* __restrict__ out,
                                                     const int* __restrict__ flag) {
    __shared__ ushort As[64 * 64];    // 8 KiB
    __shared__ ushort Bs[128 * 64];   // 16 KiB
    int tid  = threadIdx.x;
    int wave = tid >> 6;
    int lane = tid & 63;
    int l16  = lane & 15;
    int quad = lane >> 4;
    int m0   = blockIdx.y * 64;
    int n0   = blockIdx.x * 128;
    const int K = 1024;

    f32x4 acc[4][2];
#pragma unroll
    for (int i = 0; i < 4; ++i)
#pragma unroll
        for (int j = 0; j < 2; ++j) acc[i][j] = (f32x4){0.f, 0.f, 0.f, 0.f};

    int lrow = lane >> 3;
    int gcol = ((lane & 7) ^ lrow) * 8;
    int sw   = l16 & 7;

    for (int kt = 0; kt < 16; ++kt) {
        int k0 = kt * 64;
        // A: 8 chunks (2 per wave); B: 16 chunks (4 per wave)
#pragma unroll
        for (int j = 0; j < 2; ++j) {
            int chunk = wave * 2 + j;
            int grow  = chunk * 8 + lrow;
            async_cp16(&A[(size_t)(m0 + grow) * K + k0 + gcol], &As[chunk * 512]);
        }
#pragma unroll
        for (int j = 0; j < 4; ++j) {
            int chunk = wave * 4 + j;
            int grow  = chunk * 8 + lrow;
            async_cp16(&Bt[(size_t)(n0 + grow) * K + k0 + gcol], &Bs[chunk * 512]);
        }
        __syncthreads();

#pragma unroll
        for (int kb = 0; kb < 2; ++kb) {
            bf16x8 af[4], bf[2];
#pragma unroll
            for (int i = 0; i < 4; ++i)
                af[i] = *(const bf16x8*)&As[(i * 16 + l16) * 64 +
                                            (((kb * 4 + quad) ^ sw) << 3)];
#pragma unroll
            for (int j = 0; j < 2; ++j)
                bf[j] = *(const bf16x8*)&Bs[(wave * 32 + j * 16 + l16) * 64 +
                                            (((kb * 4 + quad) ^ sw) << 3)];
#pragma unroll
            for (int i = 0; i < 4; ++i)
#pragma unroll
                for (int j = 0; j < 2; ++j)
                    acc[i][j] = __builtin_amdgcn_mfma_f32_16x16x32_bf16(af[i], bf[j],
                                                                        acc[i][j], 0, 0, 0);
        }
        __syncthreads();
    }

    int outf32 = *flag;
#pragma unroll
    for (int j = 0; j < 2; ++j) {
        int n = n0 + wave * 32 + j * 16 + l16;
        float bv = bias[n];
#pragma unroll
        for (int i = 0; i < 4; ++i)
#pragma unroll
            for (int r = 0; r < 4; ++r) {
                int m = m0 + i * 16 + quad * 4 + r;
                float v = acc[i][j][r] + bv;
                if (outf32) ((float*)out)[(size_t)m * D_DIM + n] = v;
                else        ((ushort*)out)[(size_t)m * D_DIM + n] = f2bf(v);
            }
    }
}

// ---------------------------------------------------------------------------
// Causal attention v3: 32x32x16 MFMAs (halves LDS bytes/FLOP -- kernel was
// LDS-read-BW-bound: 16 ds_read_b128 per wave-tile at ~12cyc dominates the
// CU-shared LDS pipe; MfmaUtil was 15%).
//  - 128-query blocks, 4 waves x 32 queries each, 64-key tiles.
//  - K/V staged via async global_load_lds, XOR-swizzled double buffers.
//  - S^T = K.Q^T: A-frag = K rows (lane&31), B-frag = Q (query = lane&31).
//  - P transpose C-frag -> PV A-frag fully in-register: 16 cvt_pk_bf16 +
//    8 permlane32_swap per tile (pairs (4g,4g+1),(4g+2,4g+3) -> words; a
//    single lo/hi-half swap aligns key-halves).
//  - rsum reduce = one shfl_xor(32); inv broadcast by per-lane shfl.
//  - waves 0,1 skip final (fully masked) tile; wave-dependent diagonal tile.
// qt pairing (y, y+8) -> (y, 23-y): per-CU tile-rounds constant (34).
// Q (pre-scaled 0.125*log2e), K: (BH,S,64) bf16.  Vt: (BH,64,S) bf16.
// ---------------------------------------------------------------------------
__global__ __launch_bounds__(256, 2) void attn_kernel(const ushort* __restrict__ Qg,
                                                      const ushort* __restrict__ Kg,
                                                      const ushort* __restrict__ Vt,
                                                      ushort* __restrict__ attn_out) {
    __shared__ ushort Ks[2][64 * 64];   // 16 KiB (double buffer)
    __shared__ ushort Vs[2][64 * 64];   // 16 KiB
    int tid  = threadIdx.x;
    int wave = tid >> 6;
    int lane = tid & 63;
    int l31  = lane & 31;
    int hi   = lane >> 5;
    int sw7  = lane & 7;
    int bh   = blockIdx.x;
    int y    = blockIdx.y;              // 0..15
    int qt   = (y < 8) ? y : (23 - y);  // pair (y,y+8): rounds sum constant
    int q0   = qt * 128;

    const ushort* Qb = Qg + (size_t)bh * S_DIM * HD_DIM;
    const ushort* Kb = Kg + (size_t)bh * S_DIM * HD_DIM;
    const ushort* Vb = Vt + (size_t)bh * HD_DIM * S_DIM;

    // Q fragments (B-operand: n=query=l31, k=hd = kk*16 + hi*8 + e)
    bf16x8 qf[4];
#pragma unroll
    for (int kk = 0; kk < 4; ++kk)
        qf[kk] = *(const bf16x8*)&Qb[(size_t)(q0 + wave * 32 + l31) * HD_DIM +
                                     kk * 16 + hi * 8];

    f32x16 o[2];
#pragma unroll
    for (int n = 0; n < 2; ++n)
#pragma unroll
        for (int r = 0; r < 16; ++r) o[n][r] = 0.f;
    float rsum = 0.f;

    int lrow = lane >> 3;                 // staging row within 8-row chunk
    int gcol = ((lane & 7) ^ lrow) * 8;   // swizzled source column (elems)

    // stage tile 0 -> buf 0 (2 cp16 K + 2 cp16 V per thread)
#pragma unroll
    for (int j = 0; j < 2; ++j) {
        int chunk = wave * 2 + j;
        int grow  = chunk * 8 + lrow;
        async_cp16(&Kb[(size_t)grow * HD_DIM + gcol], &Ks[0][chunk * 512]);
        async_cp16(&Vb[(size_t)grow * S_DIM + gcol], &Vs[0][chunk * 512]);
    }

    int ntiles = 2 * qt + 2;      // keys 0 .. (qt+1)*128-1
    int p = 0;
    for (int t = 0; t < ntiles; ++t) {
        // implicit vmcnt(0) drain + barrier: tile t visible, buf p^1 free
        __syncthreads();
        if (t + 1 < ntiles) {
            int k1 = (t + 1) * 64;
#pragma unroll
            for (int j = 0; j < 2; ++j) {
                int chunk = wave * 2 + j;
                int grow  = chunk * 8 + lrow;
                async_cp16(&Kb[(size_t)(k1 + grow) * HD_DIM + gcol],
                           &Ks[p ^ 1][chunk * 512]);
                async_cp16(&Vb[(size_t)grow * S_DIM + k1 + gcol],
                           &Vs[p ^ 1][chunk * 512]);
            }
        }

        // final tile fully masked for waves 0,1 (queries < k0): skip compute
        if (!(t == ntiles - 1 && wave < 2)) {
            int k0 = t * 64;

            // ---- S^T = K Q^T (A=K rows mb*32+l31, k-chunk 2j+hi) ----
            f32x16 sc[2];
#pragma unroll
            for (int n = 0; n < 2; ++n)
#pragma unroll
                for (int r = 0; r < 16; ++r) sc[n][r] = 0.f;
            __builtin_amdgcn_s_setprio(1);
#pragma unroll
            for (int j = 0; j < 4; ++j)
#pragma unroll
                for (int mb = 0; mb < 2; ++mb) {
                    bf16x8 kf = *(const bf16x8*)&Ks[p][(mb * 32 + l31) * 64 +
                                                       (((2 * j + hi) ^ sw7) << 3)];
                    sc[mb] = __builtin_amdgcn_mfma_f32_32x32x16_bf16(kf, qf[j],
                                                                     sc[mb], 0, 0, 0);
                }
            __builtin_amdgcn_s_setprio(0);

            // ---- hoist V B-frags (overlap the softmax VALU chain) ----
            bf16x8 vf[4][2];
#pragma unroll
            for (int j = 0; j < 4; ++j)
#pragma unroll
                for (int nb = 0; nb < 2; ++nb)
                    vf[j][nb] = *(const bf16x8*)&Vs[p][(nb * 32 + l31) * 64 +
                                                       (((2 * j + hi) ^ sw7) << 3)];

            // ---- causal mask: wave-dependent diagonal tile ----
            if (t == ntiles - 2 + (wave >> 1)) {
                int qglob = q0 + wave * 32 + l31;
#pragma unroll
                for (int mb = 0; mb < 2; ++mb)
#pragma unroll
                    for (int r = 0; r < 16; ++r) {
                        int key = k0 + mb * 32 + (r & 3) + 8 * (r >> 2) + 4 * hi;
                        if (key > qglob) sc[mb][r] = -1e30f;
                    }
            }

            // ---- exp2 + row-sum + pack + in-register half-swap transpose ----
            bf16x8 pf[4];
#pragma unroll
            for (int mb = 0; mb < 2; ++mb) {
                unsigned int W[8];
#pragma unroll
                for (int g = 0; g < 4; ++g) {
                    float e0 = __builtin_amdgcn_exp2f(sc[mb][4 * g + 0]);
                    float e1 = __builtin_amdgcn_exp2f(sc[mb][4 * g + 1]);
                    float e2 = __builtin_amdgcn_exp2f(sc[mb][4 * g + 2]);
                    float e3 = __builtin_amdgcn_exp2f(sc[mb][4 * g + 3]);
                    rsum += (e0 + e1) + (e2 + e3);
                    W[2 * g]     = cvt_pk_bf16(e0, e1);
                    W[2 * g + 1] = cvt_pk_bf16(e2, e3);
                }
                // lo-lane holds keys {8g,8g+1,8g+2,8g+3}; hi-lane +4.
                // swap lo/hi halves pairwise to form A-frag key order 0..15.
                pl32swap(W[0], W[2]); pl32swap(W[1], W[3]);
                pl32swap(W[4], W[6]); pl32swap(W[5], W[7]);
                union { unsigned int u[4]; bf16x8 v; } c0, c1;
                c0.u[0] = W[0]; c0.u[1] = W[1]; c0.u[2] = W[2]; c0.u[3] = W[3];
                c1.u[0] = W[4]; c1.u[1] = W[5]; c1.u[2] = W[6]; c1.u[3] = W[7];
                pf[2 * mb]     = c0.v;
                pf[2 * mb + 1] = c1.v;
            }

            // ---- PV: O += P.V (A=pf, B=V frags in regs) ----
            __builtin_amdgcn_s_setprio(1);
#pragma unroll
            for (int j = 0; j < 4; ++j)
#pragma unroll
                for (int nb = 0; nb < 2; ++nb)
                    o[nb] = __builtin_amdgcn_mfma_f32_32x32x16_bf16(pf[j], vf[j][nb],
                                                                    o[nb], 0, 0, 0);
            __builtin_amdgcn_s_setprio(0);
        }
        p ^= 1;
    }

    // total row sum: lanes l and l+32 hold complementary key halves
    rsum += __shfl_xor(rsum, 32, 64);
    float inv = 1.f / rsum;       // per-lane: query l31's inverse sum

    // epilogue: o C-frag: col = hd = nb*32+l31, row = query (r&3)+8(r>>2)+4hi
    int b = bh >> 4, h = bh & 15;
#pragma unroll
    for (int nb = 0; nb < 2; ++nb)
#pragma unroll
        for (int r = 0; r < 16; ++r) {
            int qrow = (r & 3) + 8 * (r >> 2) + 4 * hi;
            float iv = __shfl(inv, qrow, 64);
            int q = q0 + wave * 32 + qrow;
            attn_out[(size_t)(b * S_DIM + q) * D_DIM + h * HD_DIM + nb * 32 + l31] =
                f2bf(o[nb][r] * iv);
        }
}

// ---------------------------------------------------------------------------
extern "C" void kernel_launch(void* const* d_in, const int* in_sizes, int n_in,
                              void* d_out, int out_size, void* d_ws, size_t ws_size,
                              hipStream_t stream) {
    const void* x  = d_in[0];
    const void* Wq = d_in[1];
    const void* bq = d_in[2];
    const void* Wk = d_in[3];
    const void* bk = d_in[4];
    const void* Wv = d_in[5];
    const void* bv = d_in[6];
    const void* Wo = d_in[7];
    const void* bo = d_in[8];
    // d_in[9] = mask: exactly causal tril, handled analytically.

    char* ws = (char*)d_ws;
    const size_t MB = 1024 * 1024;
    const size_t base = 64 * 1024;
    int*    flag   = (int*)ws;
    float*  biasf  = (float*)(ws + 4096);
    ushort* xc     = (ushort*)(ws + base);                  // 8 MiB; reused as attn later
    ushort* Wqkvt  = (ushort*)(ws + base + 8  * MB);        // 6 MiB (3072x1024)
    ushort* Wot    = (ushort*)(ws + base + 14 * MB);        // 2 MiB
    ushort* Qc     = (ushort*)(ws + base + 16 * MB);        // Q,K slices (BH,S,64)
    ushort* Vtp    = (ushort*)(ws + base + 40 * MB);        // 8 MiB (BH,64,S), direct
    ushort* attn   = xc;                                    // xc dead before attn writes

    dim3 tb(256);

    detect_kernel<<<1, tb, 0, stream>>>((const ushort*)x, flag);

    dim3 pg(16, 16, 6);
    prep_kernel<<<pg, tb, 0, stream>>>(x, Wq, Wk, Wv, Wo, bq, bk, bv, bo,
                                       xc, Wqkvt, Wot, biasf, flag);

    // Fused QKV projection: (4096x1024) x (3072x1024)^T; V written transposed
    dim3 gq(3 * D_DIM / 128, (B_DIM * S_DIM) / 128);   // (24, 32)
    gemm128_kernel<<<gq, tb, 0, stream>>>(xc, Wqkvt, biasf, Qc, Vtp);

    dim3 ag(B_DIM * H_DIM, S_DIM / 128);               // (32, 16) = 512 blocks
    attn_kernel<<<ag, tb, 0, stream>>>(Qc, Qc + (size_t)B_DIM * H_DIM * S_DIM * HD_DIM,
                                       Vtp, attn);

    dim3 go(D_DIM / 128, (B_DIM * S_DIM) / 64);        // (8, 64) = 512 blocks
    gemm64_kernel<<<go, tb, 0, stream>>>(attn, Wot, biasf + 3072, d_out, flag);
}